// Round 18
// baseline (148.082 us; speedup 1.0000x reference)
//
#include <hip/hip_runtime.h>
#include <math.h>

#define HW 16384
#define NPTS 1024
#define LOG_N 6.2383246250395075
#define RHO_C 0.09
#define SCALE_F 16384.0f
#define INV_SCALE2 3.725290298461914e-09  // 2^-28, exact
#define NTILES 36                          // 8x8 upper triangle

typedef _Float16 f16x8 __attribute__((ext_vector_type(8)));
typedef float f32x4 __attribute__((ext_vector_type(4)));

typedef __attribute__((address_space(1))) const void gvoid_t;
typedef __attribute__((address_space(3))) void svoid_t;

__device__ __forceinline__ void tri_map(int tt, int& ti, int& tj) {
  int a = 0, r = tt;
  while (r >= 8 - a) { r -= 8 - a; ++a; }
  ti = a; tj = a + r;
}

// ---------------------------------------------------------------------------
// Convert fp32 P=[nd;gt] (1024 x 16384) into scaled fp16 hi/lo split, stored
// K-tiled: hi_t[k64][row][64], groups pre-swizzled by g ^ (row&7) (GEMM's
// conflict-free LDS image). Wave-tile = 16 rows x one k64; an 8-lane group
// owns ONE row -> 256B contiguous read + full-128B-line write per row.
// ---------------------------------------------------------------------------
__global__ __launch_bounds__(256)
void convert_split_k(const float* __restrict__ nd, const float* __restrict__ gt,
                     _Float16* __restrict__ hi_t, _Float16* __restrict__ lo_t) {
  const int wt = blockIdx.x * 4 + (threadIdx.x >> 6);  // wave-tile 0..16383
  const int lane = threadIdx.x & 63;
  const int k64 = wt >> 6;         // 0..255
  const int rb = (wt & 63) << 4;   // row-block base (multiple of 16)
  const int g = lane & 7;
#pragma unroll
  for (int p = 0; p < 2; ++p) {
    const int row = rb + p * 8 + (lane >> 3);
    const float* __restrict__ src =
        (row < 512 ? nd + (size_t)row * HW : gt + (size_t)(row - 512) * HW) +
        k64 * 64 + g * 8;
    const float4 v0 = *(const float4*)(src);
    const float4 v1 = *(const float4*)(src + 4);
    const float x[8] = {v0.x, v0.y, v0.z, v0.w, v1.x, v1.y, v1.z, v1.w};
    f16x8 h, l;
#pragma unroll
    for (int j = 0; j < 8; ++j) {
      const float xs = x[j] * SCALE_F;
      const _Float16 hh = (_Float16)xs;
      h[j] = hh;
      l[j] = (_Float16)(xs - (float)hh);
    }
    const size_t o = ((size_t)k64 * 1024 + row) * 64 + (size_t)((g ^ (row & 7)) * 8);
    *(f16x8*)(hi_t + o) = h;
    *(f16x8*)(lo_t + o) = l;
  }
}

// ---------------------------------------------------------------------------
// Upper-triangle tiles (G symmetric). 128x128 tile, 8 waves, BK=64, 3-pass
// f16 split MFMA, 2-phase dbuf LDS (1 __syncthreads/K-step), fragment reads
// issued BEFORE the next-tile stage (r17: stage's LDS writes land during the
// MFMA window instead of colliding with the MFMA-gating ds_read burst).
// Best of seven measured schedules: 53us, MfmaUtil 44-45%.
// Wave-pair K-split: 4 pair-tiles (64x64) x 2 K-halves; pair halves summed
// via LDS in the epilogue. Diagonal tiles stage A only.
// ---------------------------------------------------------------------------
__global__ __launch_bounds__(512, 2)
void gemm_mfma_k(const _Float16* __restrict__ hi_t, const _Float16* __restrict__ lo_t,
                 float* __restrict__ part, int ns) {
  extern __shared__ _Float16 lds[];  // [2 buf][Ahi,Alo,Bhi,Blo][8192]

  // bijective XCD-chunked swizzle (m204 form)
  const int nwg = NTILES * ns;
  const int b = blockIdx.x;
  const int k8 = b & 7, i8 = b >> 3;
  const int q8 = nwg >> 3, r8 = nwg & 7;
  const int start = (k8 < r8) ? k8 * (q8 + 1) : r8 * (q8 + 1) + (k8 - r8) * q8;
  const int lin = start + i8;
  const int c = lin / NTILES, tt = lin - c * NTILES;

  int ti, tj;
  tri_map(tt, ti, tj);
  const bool dtile = (ti == tj);
  const int q = 256 / ns, rm = 256 - q * ns;
  const int kt0 = c * q + (c < rm ? c : rm);
  const int nkt = q + (c < rm ? 1 : 0);
  const int t = threadIdx.x;
  const int lane = t & 63, w = t >> 6;       // 8 waves
  const int pr = (w >> 1) & 1, pc = w & 1;   // pair tile (64x64) coords
  const int h = w >> 2;                      // K-half: kk slice index
  const int rlow = lane & 15, g0 = lane >> 4;
  const int sw = rlow & 7;
  const int boff = dtile ? 0 : 16384;        // B reads alias A image on diagonal

  f32x4 acc[4][4];
#pragma unroll
  for (int m = 0; m < 4; ++m)
#pragma unroll
    for (int n = 0; n < 4; ++n) acc[m][n] = (f32x4){0.f, 0.f, 0.f, 0.f};

#define STAGE(BUF, KT)                                                          \
  {                                                                             \
    const size_t tb_ = (size_t)(KT) * 65536;                                    \
    const size_t ga_ = tb_ + (size_t)ti * 8192 + w * 1024 + lane * 8;           \
    _Float16* lb_ = lds + (BUF) * 32768 + w * 1024;                             \
    __builtin_amdgcn_global_load_lds((gvoid_t*)(hi_t + ga_), (svoid_t*)(lb_), 16, 0, 0);               \
    __builtin_amdgcn_global_load_lds((gvoid_t*)(hi_t + ga_ + 512), (svoid_t*)(lb_ + 512), 16, 0, 0);   \
    __builtin_amdgcn_global_load_lds((gvoid_t*)(lo_t + ga_), (svoid_t*)(lb_ + 8192), 16, 0, 0);        \
    __builtin_amdgcn_global_load_lds((gvoid_t*)(lo_t + ga_ + 512), (svoid_t*)(lb_ + 8704), 16, 0, 0);  \
    if (!dtile) {                                                               \
      const size_t gb_ = tb_ + (size_t)tj * 8192 + w * 1024 + lane * 8;         \
      __builtin_amdgcn_global_load_lds((gvoid_t*)(hi_t + gb_), (svoid_t*)(lb_ + 16384), 16, 0, 0);     \
      __builtin_amdgcn_global_load_lds((gvoid_t*)(hi_t + gb_ + 512), (svoid_t*)(lb_ + 16896), 16, 0, 0);\
      __builtin_amdgcn_global_load_lds((gvoid_t*)(lo_t + gb_), (svoid_t*)(lb_ + 24576), 16, 0, 0);     \
      __builtin_amdgcn_global_load_lds((gvoid_t*)(lo_t + gb_ + 512), (svoid_t*)(lb_ + 25088), 16, 0, 0);\
    }                                                                           \
  }

  STAGE(0, kt0);
  __syncthreads();

  int cur = 0;
  for (int ks = 0; ks < nkt; ++ks) {
    // fragment reads FIRST: uncontended LDS at step start (MFMA-gating path)
    const _Float16* __restrict__ bb = lds + cur * 32768;
    const int pe = ((h * 4 + g0) ^ sw) * 8;
    f16x8 ah[4], al[4], bh[4], bl[4];
#pragma unroll
    for (int m = 0; m < 4; ++m) {
      const int ra = pr * 64 + m * 16 + rlow;
      ah[m] = *(const f16x8*)(bb + ra * 64 + pe);
      al[m] = *(const f16x8*)(bb + 8192 + ra * 64 + pe);
      const int rb = pc * 64 + m * 16 + rlow;
      bh[m] = *(const f16x8*)(bb + boff + rb * 64 + pe);
      bl[m] = *(const f16x8*)(bb + boff + 8192 + rb * 64 + pe);
    }

    // stage for ks+1 issued after the reads: its LDS writes return from L2
    // during the MFMA window below, when the LDS unit is otherwise idle.
    if (ks + 1 < nkt) STAGE(cur ^ 1, kt0 + ks + 1);
    __builtin_amdgcn_sched_barrier(0);  // pin stage issue above the MFMA cluster

    __builtin_amdgcn_s_setprio(1);
#pragma unroll
    for (int m = 0; m < 4; ++m)
#pragma unroll
      for (int n = 0; n < 4; ++n) {
        acc[m][n] = __builtin_amdgcn_mfma_f32_16x16x32_f16(ah[m], bh[n], acc[m][n], 0, 0, 0);
        acc[m][n] = __builtin_amdgcn_mfma_f32_16x16x32_f16(al[m], bh[n], acc[m][n], 0, 0, 0);
        acc[m][n] = __builtin_amdgcn_mfma_f32_16x16x32_f16(ah[m], bl[n], acc[m][n], 0, 0, 0);
      }
    __builtin_amdgcn_s_setprio(0);
    __syncthreads();  // drains stage (vmcnt0) + read-done for both buffers
    cur ^= 1;
  }

  // Pair-sum epilogue: K-half h=1 dumps acc to LDS; h=0 adds and writes C.
  float* red = (float*)lds;  // 4 pairs x 16KB, LDS is free after the loop
  if (h == 1) {
    float* wb = red + (w & 3) * 4096;
#pragma unroll
    for (int m = 0; m < 4; ++m)
#pragma unroll
      for (int n = 0; n < 4; ++n)
        *(f32x4*)(wb + (m * 4 + n) * 256 + lane * 4) = acc[m][n];
  }
  __syncthreads();
  if (h == 0) {
    float* wb = red + w * 4096;  // w in 0..3 == pair id
    float* __restrict__ dst = part + ((size_t)c * NTILES + tt) * 16384;
    const int clb = pc * 64 + rlow;
    const int rlb = pr * 64 + g0 * 4;
#pragma unroll
    for (int m = 0; m < 4; ++m)
#pragma unroll
      for (int n = 0; n < 4; ++n) {
        const f32x4 o = *(const f32x4*)(wb + (m * 4 + n) * 256 + lane * 4);
        const f32x4 s = acc[m][n] + o;
#pragma unroll
        for (int p = 0; p < 4; ++p)
          dst[(rlb + m * 16 + p) * 128 + clb + n * 16] = s[p];
      }
  }
#undef STAGE
}

// ---------------------------------------------------------------------------
// Sum split-K partials (fp64), unscale, write G tile + mirrored tile (LDS
// transpose), extract diagonal. Grid: 36 tiles x 16 slabs of 8 rows = 576.
// ---------------------------------------------------------------------------
__global__ __launch_bounds__(256)
void reduce_tiles_k(const float* __restrict__ part, float* __restrict__ G,
                    float* __restrict__ diag, int nsplit) {
  __shared__ float sl[8][129];
  const int blk = blockIdx.x;  // 0..575
  const int tt = blk >> 4, s = blk & 15;
  int ti, tj;
  tri_map(tt, ti, tj);
  const int t = threadIdx.x;
  const int base_in = tt * 16384 + s * 1024;

  float vals[4];
#pragma unroll
  for (int j = 0; j < 4; ++j) {
    const int idx = j * 256 + t;  // 0..1023 within slab
    double a = 0.0;
    for (int c = 0; c < nsplit; ++c)
      a += (double)part[(size_t)c * (NTILES * 16384) + base_in + idx];
    vals[j] = (float)(a * INV_SCALE2);
  }
#pragma unroll
  for (int j = 0; j < 4; ++j) {
    const int idx = j * 256 + t;
    const int r = idx >> 7, cl = idx & 127;
    const int R = ti * 128 + s * 8 + r, C = tj * 128 + cl;
    G[(size_t)R * NPTS + C] = vals[j];
    if (R == C) diag[R] = vals[j];
    sl[r][cl] = vals[j];
  }
  if (ti == tj) return;
  __syncthreads();
#pragma unroll
  for (int j = 0; j < 4; ++j) {
    const int idx = j * 256 + t;
    const int r = idx & 7, cl = idx >> 3;
    G[(size_t)(tj * 128 + cl) * NPTS + ti * 128 + s * 8 + r] = sl[r][cl];
  }
}

// ---------------------------------------------------------------------------
// One symmetric Sinkhorn phase: 512 blocks x 4 waves; 1 wave = 1 row-task.
// pot layout: [0]=f_ba, [1]=g_ab, [2]=f_aa, [3]=g_bb (512 doubles each).
// (Fusion verdict after r3/r5/r15: grid-wide sync costs >=10us/phase on
// this part regardless of mechanism; 12 small launches are the floor.)
// ---------------------------------------------------------------------------
__global__ __launch_bounds__(256)
void sinkhorn_phase_k(const float* __restrict__ G, const float* __restrict__ diag,
                      const double* __restrict__ src, double* __restrict__ dst,
                      double eps, double inv_eps, double damp, int use_pot,
                      int do_avg) {
  const int w = threadIdx.x >> 6, lane = threadIdx.x & 63;
  const int id = blockIdx.x * 4 + w;  // 0..2047
  const int which = id >> 9, r = id & 511;
  int row_pt, col_base, pot_idx;
  if (which == 0)      { row_pt = r;       col_base = 512; pot_idx = 1; }
  else if (which == 1) { row_pt = 512 + r; col_base = 0;   pot_idx = 0; }
  else if (which == 2) { row_pt = r;       col_base = 0;   pot_idx = 2; }
  else                 { row_pt = 512 + r; col_base = 512; pot_idx = 3; }

  const double dr = (double)diag[row_pt];
  const double* __restrict__ pot = src + pot_idx * 512;
  const float* __restrict__ Grow = G + (size_t)row_pt * NPTS + col_base;
  const float* __restrict__ dcol = diag + col_base;

  double arg[8];
  double m = -1.0e300;
#pragma unroll
  for (int u = 0; u < 8; ++u) {
    const int j = lane + u * 64;
    const double C = 0.5 * (dr + (double)dcol[j]) - (double)Grow[j];
    const double p = use_pot ? pot[j] : 0.0;
    const double a = (p - C) * inv_eps - LOG_N;
    arg[u] = a;
    m = fmax(m, a);
  }
#pragma unroll
  for (int off = 32; off > 0; off >>= 1) m = fmax(m, __shfl_xor(m, off));
  double s = 0.0;
#pragma unroll
  for (int u = 0; u < 8; ++u) s += exp(arg[u] - m);
#pragma unroll
  for (int off = 32; off > 0; off >>= 1) s += __shfl_xor(s, off);
  if (lane == 0) {
    const double lse = m + log(s);
    const double val = -eps * lse * damp;
    dst[which * 512 + r] = do_avg ? 0.5 * (src[which * 512 + r] + val) : val;
  }
}

// ---------------------------------------------------------------------------
// Final extrapolation + loss, fused: the final potentials are consumed ONLY
// by the loss, so don't store them -- each wave's lane-0 turns its task's
// val into sgn*exp(-val/rho), block-reduces in LDS, one f64 device-scope
// atomicAdd per block (ordered before a counter add by vmcnt(0)); the 512th
// arrival reads the accumulator and writes out. Single-pass, no spin.
// ---------------------------------------------------------------------------
__global__ __launch_bounds__(256)
void sinkhorn_final_k(const float* __restrict__ G, const float* __restrict__ diag,
                      const double* __restrict__ src, double* lacc, unsigned* cnt2,
                      float* __restrict__ out, int out_size,
                      double eps, double inv_eps, double damp, double w_loss) {
  const int wv = threadIdx.x >> 6, lane = threadIdx.x & 63;
  const int id = blockIdx.x * 4 + wv;  // 0..2047
  const int which = id >> 9, r = id & 511;
  int row_pt, col_base, pot_idx;
  if (which == 0)      { row_pt = r;       col_base = 512; pot_idx = 1; }
  else if (which == 1) { row_pt = 512 + r; col_base = 0;   pot_idx = 0; }
  else if (which == 2) { row_pt = r;       col_base = 0;   pot_idx = 2; }
  else                 { row_pt = 512 + r; col_base = 512; pot_idx = 3; }

  const double dr = (double)diag[row_pt];
  const double* __restrict__ pot = src + pot_idx * 512;
  const float* __restrict__ Grow = G + (size_t)row_pt * NPTS + col_base;
  const float* __restrict__ dcol = diag + col_base;

  double arg[8];
  double m = -1.0e300;
#pragma unroll
  for (int u = 0; u < 8; ++u) {
    const int j = lane + u * 64;
    const double C = 0.5 * (dr + (double)dcol[j]) - (double)Grow[j];
    const double a = (pot[j] - C) * inv_eps - LOG_N;
    arg[u] = a;
    m = fmax(m, a);
  }
#pragma unroll
  for (int off = 32; off > 0; off >>= 1) m = fmax(m, __shfl_xor(m, off));
  double s = 0.0;
#pragma unroll
  for (int u = 0; u < 8; ++u) s += exp(arg[u] - m);
#pragma unroll
  for (int off = 32; off > 0; off >>= 1) s += __shfl_xor(s, off);

  __shared__ double csum[4];
  if (lane == 0) {
    const double val = -eps * (m + log(s)) * damp;  // final potential
    const double sgn = (which >= 2) ? 1.0 : -1.0;   // +f_aa,+g_bb ; -f_ba,-g_ab
    csum[wv] = sgn * exp(-val / RHO_C);
  }
  __syncthreads();
  if (threadIdx.x == 0) {
    const double bs = csum[0] + csum[1] + csum[2] + csum[3];
    atomicAdd(lacc, bs);                              // device-scope f64
    asm volatile("s_waitcnt vmcnt(0)" ::: "memory");  // add complete before count
    const unsigned old = atomicAdd(cnt2, 1u);
    if (old == 511u) {                                // all 512 adds visible
      const double tot =
          __hip_atomic_load(lacc, __ATOMIC_RELAXED, __HIP_MEMORY_SCOPE_AGENT);
      out[0] = (float)(w_loss * tot * (1.0 / 512.0));
      for (int i = 1; i < out_size; ++i) out[i] = 0.f;
    }
  }
}

extern "C" void kernel_launch(void* const* d_in, const int* in_sizes, int n_in,
                              void* d_out, int out_size, void* d_ws, size_t ws_size,
                              hipStream_t stream) {
  const float* nd = (const float*)d_in[1];
  const float* gt = (const float*)d_in[2];
  float* out = (float*)d_out;
  char* ws = (char*)d_ws;

  const size_t GM = (size_t)NPTS * NPTS;     // 1M elems
  const size_t P16 = (size_t)NPTS * HW * 2;  // 32 MB per half
  int nsplit = 7;                             // 36*7 = 252 blocks @ 1/CU: 1 round
  while (nsplit > 1 &&
         2 * P16 + (size_t)nsplit * NTILES * 16384 * 4 + GM * 4 + 131072 > ws_size)
    nsplit >>= 1;

  _Float16* hi_t = (_Float16*)ws;
  _Float16* lo_t = (_Float16*)(ws + P16);
  float* part = (float*)(ws + 2 * P16);
  const size_t partsz = (size_t)nsplit * NTILES * 16384 * 4;
  float* G = (float*)(ws + 2 * P16 + partsz);
  float* diag = (float*)(ws + 2 * P16 + partsz + GM * 4);
  double* pots = (double*)(ws + 2 * P16 + partsz + GM * 4 + 8192);
  double* lacc = (double*)(ws + 2 * P16 + partsz + GM * 4 + 8192 + 49152);
  unsigned* cnt2 = (unsigned*)(ws + 2 * P16 + partsz + GM * 4 + 8192 + 49152 + 64);

  hipFuncSetAttribute((const void*)gemm_mfma_k,
                      hipFuncAttributeMaxDynamicSharedMemorySize, 131072);

  hipMemsetAsync(lacc, 0, 128, stream);  // zero loss accumulator + counter
  convert_split_k<<<4096, 256, 0, stream>>>(nd, gt, hi_t, lo_t);
  gemm_mfma_k<<<NTILES * nsplit, 512, 131072, stream>>>(hi_t, lo_t, part, nsplit);
  reduce_tiles_k<<<576, 256, 0, stream>>>(part, G, diag, nsplit);

  const double eps_list[9] = {1.0, 1.0, 0.25, 0.0625, 0.015625,
                              0.00390625, 0.0009765625, 0.000244140625, 1e-4};
  double* p0 = pots;
  double* p1 = pots + 2048;
  {  // init at eps0 = 1.0, no inner potentials, no averaging
    const double eps = 1.0, d = 1.0 / (1.0 + eps / RHO_C);
    sinkhorn_phase_k<<<512, 256, 0, stream>>>(G, diag, p1, p0, eps, 1.0 / eps, d, 0, 0);
  }
  double* src = p0;
  double* dst = p1;
  for (int k = 0; k < 9; ++k) {  // symmetric averaged updates
    const double eps = eps_list[k], d = 1.0 / (1.0 + eps / RHO_C);
    sinkhorn_phase_k<<<512, 256, 0, stream>>>(G, diag, src, dst, eps, 1.0 / eps, d, 1, 1);
    double* tmp = src; src = dst; dst = tmp;
  }
  {  // final extrapolation at blur^2 fused with the loss reduction
    const double eps = 1e-4, d = 1.0 / (1.0 + eps / RHO_C);
    sinkhorn_final_k<<<512, 256, 0, stream>>>(G, diag, src, lacc, cnt2, out, out_size,
                                              eps, 1.0 / eps, d, RHO_C + 1e-4 * 0.5);
  }
}

// Round 19
// 137.297 us; speedup vs baseline: 1.0786x; 1.0786x over previous
//
#include <hip/hip_runtime.h>
#include <math.h>

#define HW 16384
#define NPTS 1024
#define LOG_N 6.2383246250395075
#define RHO_C 0.09
#define SCALE_F 16384.0f
#define INV_SCALE2 3.725290298461914e-09  // 2^-28, exact
#define NTILES 36                          // 8x8 upper triangle

typedef _Float16 f16x8 __attribute__((ext_vector_type(8)));
typedef float f32x4 __attribute__((ext_vector_type(4)));

typedef __attribute__((address_space(1))) const void gvoid_t;
typedef __attribute__((address_space(3))) void svoid_t;

__device__ __forceinline__ void tri_map(int tt, int& ti, int& tj) {
  int a = 0, r = tt;
  while (r >= 8 - a) { r -= 8 - a; ++a; }
  ti = a; tj = a + r;
}

// ---------------------------------------------------------------------------
// Convert fp32 P=[nd;gt] (1024 x 16384) into scaled fp16 hi/lo split, stored
// K-tiled: hi_t[k64][row][64], groups pre-swizzled by g ^ (row&7) (GEMM's
// conflict-free LDS image). Wave-tile = 16 rows x one k64; an 8-lane group
// owns ONE row -> 256B contiguous read + full-128B-line write per row.
// ---------------------------------------------------------------------------
__global__ __launch_bounds__(256)
void convert_split_k(const float* __restrict__ nd, const float* __restrict__ gt,
                     _Float16* __restrict__ hi_t, _Float16* __restrict__ lo_t) {
  const int wt = blockIdx.x * 4 + (threadIdx.x >> 6);  // wave-tile 0..16383
  const int lane = threadIdx.x & 63;
  const int k64 = wt >> 6;         // 0..255
  const int rb = (wt & 63) << 4;   // row-block base (multiple of 16)
  const int g = lane & 7;
#pragma unroll
  for (int p = 0; p < 2; ++p) {
    const int row = rb + p * 8 + (lane >> 3);
    const float* __restrict__ src =
        (row < 512 ? nd + (size_t)row * HW : gt + (size_t)(row - 512) * HW) +
        k64 * 64 + g * 8;
    const float4 v0 = *(const float4*)(src);
    const float4 v1 = *(const float4*)(src + 4);
    const float x[8] = {v0.x, v0.y, v0.z, v0.w, v1.x, v1.y, v1.z, v1.w};
    f16x8 h, l;
#pragma unroll
    for (int j = 0; j < 8; ++j) {
      const float xs = x[j] * SCALE_F;
      const _Float16 hh = (_Float16)xs;
      h[j] = hh;
      l[j] = (_Float16)(xs - (float)hh);
    }
    const size_t o = ((size_t)k64 * 1024 + row) * 64 + (size_t)((g ^ (row & 7)) * 8);
    *(f16x8*)(hi_t + o) = h;
    *(f16x8*)(lo_t + o) = l;
  }
}

// ---------------------------------------------------------------------------
// Upper-triangle tiles (G symmetric). 128x128 tile, 8 waves, BK=64, 3-pass
// f16 split MFMA, 2-phase dbuf LDS (1 __syncthreads/K-step), fragment reads
// issued BEFORE the next-tile stage (r17: stage's LDS writes land during the
// MFMA window instead of colliding with the MFMA-gating ds_read burst).
// Best of seven measured schedules: 53us, MfmaUtil 44-45%.
// Wave-pair K-split: 4 pair-tiles (64x64) x 2 K-halves; pair halves summed
// via LDS in the epilogue. Diagonal tiles stage A only.
// ---------------------------------------------------------------------------
__global__ __launch_bounds__(512, 2)
void gemm_mfma_k(const _Float16* __restrict__ hi_t, const _Float16* __restrict__ lo_t,
                 float* __restrict__ part, int ns) {
  extern __shared__ _Float16 lds[];  // [2 buf][Ahi,Alo,Bhi,Blo][8192]

  // bijective XCD-chunked swizzle (m204 form)
  const int nwg = NTILES * ns;
  const int b = blockIdx.x;
  const int k8 = b & 7, i8 = b >> 3;
  const int q8 = nwg >> 3, r8 = nwg & 7;
  const int start = (k8 < r8) ? k8 * (q8 + 1) : r8 * (q8 + 1) + (k8 - r8) * q8;
  const int lin = start + i8;
  const int c = lin / NTILES, tt = lin - c * NTILES;

  int ti, tj;
  tri_map(tt, ti, tj);
  const bool dtile = (ti == tj);
  const int q = 256 / ns, rm = 256 - q * ns;
  const int kt0 = c * q + (c < rm ? c : rm);
  const int nkt = q + (c < rm ? 1 : 0);
  const int t = threadIdx.x;
  const int lane = t & 63, w = t >> 6;       // 8 waves
  const int pr = (w >> 1) & 1, pc = w & 1;   // pair tile (64x64) coords
  const int h = w >> 2;                      // K-half: kk slice index
  const int rlow = lane & 15, g0 = lane >> 4;
  const int sw = rlow & 7;
  const int boff = dtile ? 0 : 16384;        // B reads alias A image on diagonal

  f32x4 acc[4][4];
#pragma unroll
  for (int m = 0; m < 4; ++m)
#pragma unroll
    for (int n = 0; n < 4; ++n) acc[m][n] = (f32x4){0.f, 0.f, 0.f, 0.f};

#define STAGE(BUF, KT)                                                          \
  {                                                                             \
    const size_t tb_ = (size_t)(KT) * 65536;                                    \
    const size_t ga_ = tb_ + (size_t)ti * 8192 + w * 1024 + lane * 8;           \
    _Float16* lb_ = lds + (BUF) * 32768 + w * 1024;                             \
    __builtin_amdgcn_global_load_lds((gvoid_t*)(hi_t + ga_), (svoid_t*)(lb_), 16, 0, 0);               \
    __builtin_amdgcn_global_load_lds((gvoid_t*)(hi_t + ga_ + 512), (svoid_t*)(lb_ + 512), 16, 0, 0);   \
    __builtin_amdgcn_global_load_lds((gvoid_t*)(lo_t + ga_), (svoid_t*)(lb_ + 8192), 16, 0, 0);        \
    __builtin_amdgcn_global_load_lds((gvoid_t*)(lo_t + ga_ + 512), (svoid_t*)(lb_ + 8704), 16, 0, 0);  \
    if (!dtile) {                                                               \
      const size_t gb_ = tb_ + (size_t)tj * 8192 + w * 1024 + lane * 8;         \
      __builtin_amdgcn_global_load_lds((gvoid_t*)(hi_t + gb_), (svoid_t*)(lb_ + 16384), 16, 0, 0);     \
      __builtin_amdgcn_global_load_lds((gvoid_t*)(hi_t + gb_ + 512), (svoid_t*)(lb_ + 16896), 16, 0, 0);\
      __builtin_amdgcn_global_load_lds((gvoid_t*)(lo_t + gb_), (svoid_t*)(lb_ + 24576), 16, 0, 0);     \
      __builtin_amdgcn_global_load_lds((gvoid_t*)(lo_t + gb_ + 512), (svoid_t*)(lb_ + 25088), 16, 0, 0);\
    }                                                                           \
  }

  STAGE(0, kt0);
  __syncthreads();

  int cur = 0;
  for (int ks = 0; ks < nkt; ++ks) {
    // fragment reads FIRST: uncontended LDS at step start (MFMA-gating path)
    const _Float16* __restrict__ bb = lds + cur * 32768;
    const int pe = ((h * 4 + g0) ^ sw) * 8;
    f16x8 ah[4], al[4], bh[4], bl[4];
#pragma unroll
    for (int m = 0; m < 4; ++m) {
      const int ra = pr * 64 + m * 16 + rlow;
      ah[m] = *(const f16x8*)(bb + ra * 64 + pe);
      al[m] = *(const f16x8*)(bb + 8192 + ra * 64 + pe);
      const int rb = pc * 64 + m * 16 + rlow;
      bh[m] = *(const f16x8*)(bb + boff + rb * 64 + pe);
      bl[m] = *(const f16x8*)(bb + boff + 8192 + rb * 64 + pe);
    }

    // stage for ks+1 issued after the reads: its LDS writes return from L2
    // during the MFMA window below, when the LDS unit is otherwise idle.
    if (ks + 1 < nkt) STAGE(cur ^ 1, kt0 + ks + 1);
    __builtin_amdgcn_sched_barrier(0);  // pin stage issue above the MFMA cluster

    __builtin_amdgcn_s_setprio(1);
#pragma unroll
    for (int m = 0; m < 4; ++m)
#pragma unroll
      for (int n = 0; n < 4; ++n) {
        acc[m][n] = __builtin_amdgcn_mfma_f32_16x16x32_f16(ah[m], bh[n], acc[m][n], 0, 0, 0);
        acc[m][n] = __builtin_amdgcn_mfma_f32_16x16x32_f16(al[m], bh[n], acc[m][n], 0, 0, 0);
        acc[m][n] = __builtin_amdgcn_mfma_f32_16x16x32_f16(ah[m], bl[n], acc[m][n], 0, 0, 0);
      }
    __builtin_amdgcn_s_setprio(0);
    __syncthreads();  // drains stage (vmcnt0) + read-done for both buffers
    cur ^= 1;
  }

  // Pair-sum epilogue: K-half h=1 dumps acc to LDS; h=0 adds and writes C.
  float* red = (float*)lds;  // 4 pairs x 16KB, LDS is free after the loop
  if (h == 1) {
    float* wb = red + (w & 3) * 4096;
#pragma unroll
    for (int m = 0; m < 4; ++m)
#pragma unroll
      for (int n = 0; n < 4; ++n)
        *(f32x4*)(wb + (m * 4 + n) * 256 + lane * 4) = acc[m][n];
  }
  __syncthreads();
  if (h == 0) {
    float* wb = red + w * 4096;  // w in 0..3 == pair id
    float* __restrict__ dst = part + ((size_t)c * NTILES + tt) * 16384;
    const int clb = pc * 64 + rlow;
    const int rlb = pr * 64 + g0 * 4;
#pragma unroll
    for (int m = 0; m < 4; ++m)
#pragma unroll
      for (int n = 0; n < 4; ++n) {
        const f32x4 o = *(const f32x4*)(wb + (m * 4 + n) * 256 + lane * 4);
        const f32x4 s = acc[m][n] + o;
#pragma unroll
        for (int p = 0; p < 4; ++p)
          dst[(rlb + m * 16 + p) * 128 + clb + n * 16] = s[p];
      }
  }
#undef STAGE
}

// ---------------------------------------------------------------------------
// Sum split-K partials (fp64), unscale, write G tile + mirrored tile (LDS
// transpose), extract diagonal. Grid: 36 tiles x 16 slabs of 8 rows = 576.
// ---------------------------------------------------------------------------
__global__ __launch_bounds__(256)
void reduce_tiles_k(const float* __restrict__ part, float* __restrict__ G,
                    float* __restrict__ diag, int nsplit) {
  __shared__ float sl[8][129];
  const int blk = blockIdx.x;  // 0..575
  const int tt = blk >> 4, s = blk & 15;
  int ti, tj;
  tri_map(tt, ti, tj);
  const int t = threadIdx.x;
  const int base_in = tt * 16384 + s * 1024;

  float vals[4];
#pragma unroll
  for (int j = 0; j < 4; ++j) {
    const int idx = j * 256 + t;  // 0..1023 within slab
    double a = 0.0;
    for (int c = 0; c < nsplit; ++c)
      a += (double)part[(size_t)c * (NTILES * 16384) + base_in + idx];
    vals[j] = (float)(a * INV_SCALE2);
  }
#pragma unroll
  for (int j = 0; j < 4; ++j) {
    const int idx = j * 256 + t;
    const int r = idx >> 7, cl = idx & 127;
    const int R = ti * 128 + s * 8 + r, C = tj * 128 + cl;
    G[(size_t)R * NPTS + C] = vals[j];
    if (R == C) diag[R] = vals[j];
    sl[r][cl] = vals[j];
  }
  if (ti == tj) return;
  __syncthreads();
#pragma unroll
  for (int j = 0; j < 4; ++j) {
    const int idx = j * 256 + t;
    const int r = idx & 7, cl = idx >> 3;
    G[(size_t)(tj * 128 + cl) * NPTS + ti * 128 + s * 8 + r] = sl[r][cl];
  }
}

// ---------------------------------------------------------------------------
// One symmetric Sinkhorn phase: 512 blocks x 4 waves; 1 wave = 1 row-task.
// pot layout: [0]=f_ba, [1]=g_ab, [2]=f_aa, [3]=g_bb (512 doubles each).
// (Fusion verdict after r3/r5/r15/r18: cross-block coordination costs more
// than a launch on this part, by every mechanism tried; 12 launches + loss
// is the floor.)
// ---------------------------------------------------------------------------
__global__ __launch_bounds__(256)
void sinkhorn_phase_k(const float* __restrict__ G, const float* __restrict__ diag,
                      const double* __restrict__ src, double* __restrict__ dst,
                      double eps, double inv_eps, double damp, int use_pot,
                      int do_avg) {
  const int w = threadIdx.x >> 6, lane = threadIdx.x & 63;
  const int id = blockIdx.x * 4 + w;  // 0..2047
  const int which = id >> 9, r = id & 511;
  int row_pt, col_base, pot_idx;
  if (which == 0)      { row_pt = r;       col_base = 512; pot_idx = 1; }
  else if (which == 1) { row_pt = 512 + r; col_base = 0;   pot_idx = 0; }
  else if (which == 2) { row_pt = r;       col_base = 0;   pot_idx = 2; }
  else                 { row_pt = 512 + r; col_base = 512; pot_idx = 3; }

  const double dr = (double)diag[row_pt];
  const double* __restrict__ pot = src + pot_idx * 512;
  const float* __restrict__ Grow = G + (size_t)row_pt * NPTS + col_base;
  const float* __restrict__ dcol = diag + col_base;

  double arg[8];
  double m = -1.0e300;
#pragma unroll
  for (int u = 0; u < 8; ++u) {
    const int j = lane + u * 64;
    const double C = 0.5 * (dr + (double)dcol[j]) - (double)Grow[j];
    const double p = use_pot ? pot[j] : 0.0;
    const double a = (p - C) * inv_eps - LOG_N;
    arg[u] = a;
    m = fmax(m, a);
  }
#pragma unroll
  for (int off = 32; off > 0; off >>= 1) m = fmax(m, __shfl_xor(m, off));
  double s = 0.0;
#pragma unroll
  for (int u = 0; u < 8; ++u) s += exp(arg[u] - m);
#pragma unroll
  for (int off = 32; off > 0; off >>= 1) s += __shfl_xor(s, off);
  if (lane == 0) {
    const double lse = m + log(s);
    const double val = -eps * lse * damp;
    dst[which * 512 + r] = do_avg ? 0.5 * (src[which * 512 + r] + val) : val;
  }
}

// ---------------------------------------------------------------------------
// Debiased unbalanced Sinkhorn loss.
// ---------------------------------------------------------------------------
__global__ __launch_bounds__(256)
void loss_k(const double* __restrict__ pot, float* __restrict__ out, int out_size,
            double w) {
  const int t = threadIdx.x;
  double s = 0.0;
  for (int i = t; i < 512; i += 256) {
    s += (exp(-pot[1024 + i] / RHO_C) - exp(-pot[i] / RHO_C)) +
         (exp(-pot[1536 + i] / RHO_C) - exp(-pot[512 + i] / RHO_C));
  }
#pragma unroll
  for (int off = 32; off > 0; off >>= 1) s += __shfl_xor(s, off);
  __shared__ double wsum[4];
  if ((t & 63) == 0) wsum[t >> 6] = s;
  __syncthreads();
  if (t == 0) {
    out[0] = (float)(w * (wsum[0] + wsum[1] + wsum[2] + wsum[3]) * (1.0 / 512.0));
    for (int i = 1; i < out_size; ++i) out[i] = 0.f;
  }
}

extern "C" void kernel_launch(void* const* d_in, const int* in_sizes, int n_in,
                              void* d_out, int out_size, void* d_ws, size_t ws_size,
                              hipStream_t stream) {
  const float* nd = (const float*)d_in[1];
  const float* gt = (const float*)d_in[2];
  float* out = (float*)d_out;
  char* ws = (char*)d_ws;

  const size_t GM = (size_t)NPTS * NPTS;     // 1M elems
  const size_t P16 = (size_t)NPTS * HW * 2;  // 32 MB per half
  int nsplit = 7;                             // 36*7 = 252 blocks @ 1/CU: 1 round
  while (nsplit > 1 &&
         2 * P16 + (size_t)nsplit * NTILES * 16384 * 4 + GM * 4 + 65536 > ws_size)
    nsplit >>= 1;

  _Float16* hi_t = (_Float16*)ws;
  _Float16* lo_t = (_Float16*)(ws + P16);
  float* part = (float*)(ws + 2 * P16);
  const size_t partsz = (size_t)nsplit * NTILES * 16384 * 4;
  float* G = (float*)(ws + 2 * P16 + partsz);
  float* diag = (float*)(ws + 2 * P16 + partsz + GM * 4);
  double* pots = (double*)(ws + 2 * P16 + partsz + GM * 4 + 8192);

  hipFuncSetAttribute((const void*)gemm_mfma_k,
                      hipFuncAttributeMaxDynamicSharedMemorySize, 131072);

  convert_split_k<<<4096, 256, 0, stream>>>(nd, gt, hi_t, lo_t);
  gemm_mfma_k<<<NTILES * nsplit, 512, 131072, stream>>>(hi_t, lo_t, part, nsplit);
  reduce_tiles_k<<<576, 256, 0, stream>>>(part, G, diag, nsplit);

  const double eps_list[9] = {1.0, 1.0, 0.25, 0.0625, 0.015625,
                              0.00390625, 0.0009765625, 0.000244140625, 1e-4};
  double* p0 = pots;
  double* p1 = pots + 2048;
  {  // init at eps0 = 1.0, no inner potentials, no averaging
    const double eps = 1.0, d = 1.0 / (1.0 + eps / RHO_C);
    sinkhorn_phase_k<<<512, 256, 0, stream>>>(G, diag, p1, p0, eps, 1.0 / eps, d, 0, 0);
  }
  double* src = p0;
  double* dst = p1;
  for (int k = 0; k < 9; ++k) {  // symmetric averaged updates
    const double eps = eps_list[k], d = 1.0 / (1.0 + eps / RHO_C);
    sinkhorn_phase_k<<<512, 256, 0, stream>>>(G, diag, src, dst, eps, 1.0 / eps, d, 1, 1);
    double* tmp = src; src = dst; dst = tmp;
  }
  {  // final extrapolation at blur^2, no averaging
    const double eps = 1e-4, d = 1.0 / (1.0 + eps / RHO_C);
    sinkhorn_phase_k<<<512, 256, 0, stream>>>(G, diag, src, dst, eps, 1.0 / eps, d, 1, 0);
    double* tmp = src; src = dst; dst = tmp;
  }
  loss_k<<<1, 256, 0, stream>>>(src, out, out_size, RHO_C + 1e-4 * 0.5);
}